// Round 1
// baseline (1356.545 us; speedup 1.0000x reference)
//
#include <hip/hip_runtime.h>
#include <hip/hip_bf16.h>

#define DD 256

// ---------------------------------------------------------------------------
// Build WT[k][j], k in [0,512): k<256 -> Wl[j][k], k>=256 -> Wr[j][k-256]
// (i.e. concatenated transposed weights so gemm does one K=512 pass)
// ---------------------------------------------------------------------------
__global__ void build_wt_kernel(const float* __restrict__ Wl,
                                const float* __restrict__ Wr,
                                float* __restrict__ WT) {
    int k = blockIdx.x;       // 0..511
    int j = threadIdx.x;      // 0..255
    float v = (k < DD) ? Wl[j * DD + k] : Wr[j * DD + (k - DD)];
    WT[k * DD + j] = v;
}

// ---------------------------------------------------------------------------
// Scatter-sum: agg[dst[e]][:] += xsrc[src[e]][:]; cnt[dst[e]] += 1
// One float4 (4 features) per thread-iteration; 64 chunk-threads per edge.
// ---------------------------------------------------------------------------
__global__ void scatter_kernel(const float* __restrict__ xsrc,
                               const int* __restrict__ src,
                               const int* __restrict__ dst,
                               float* __restrict__ agg,
                               float* __restrict__ cnt,
                               int E) {
    long long total = (long long)E * 64;
    long long stride = (long long)gridDim.x * blockDim.x;
    for (long long t = (long long)blockIdx.x * blockDim.x + threadIdx.x;
         t < total; t += stride) {
        int e = (int)(t >> 6);
        int c = (int)(t & 63);
        int s = src[e];
        int d = dst[e];
        float4 v = *(const float4*)(xsrc + (size_t)s * DD + c * 4);
        float* o = agg + (size_t)d * DD + c * 4;
        atomicAdd(o + 0, v.x);
        atomicAdd(o + 1, v.y);
        atomicAdd(o + 2, v.z);
        atomicAdd(o + 3, v.w);
        if (c == 0) atomicAdd(cnt + d, 1.0f);
    }
}

// ---------------------------------------------------------------------------
// Fused SAGE GEMM:  OUT[i][j] = act( (agg[i]/max(cnt[i],1)) . Wl[j,:]
//                                    + X[i] . Wr[j,:] + bias[j] )
// Implemented as C = Acat @ WT + bias, Acat = [agg*rs | X]  (K = 512).
// 64x64 tile, 256 threads, 4x4 register micro-tile, BK=16.
// ---------------------------------------------------------------------------
__global__ __launch_bounds__(256)
void sage_gemm_kernel(const float* __restrict__ AGG,
                      const float* __restrict__ XT,
                      const float* __restrict__ cnt,
                      const float* __restrict__ WT,   // [512][256]
                      const float* __restrict__ bias, // [256]
                      float* __restrict__ OUT,
                      int do_relu) {
    __shared__ float As[16][68];   // [k][m]  (transposed A chunk, padded)
    __shared__ float Bs[16][68];   // [k][n]  (padded)

    const int tid = threadIdx.x;
    const int tx = tid & 15;       // micro-tile col group
    const int ty = tid >> 4;       // micro-tile row group
    const int i0 = blockIdx.x * 64;
    const int j0 = blockIdx.y * 64;

    // staging roles
    const int srow = tid >> 2;     // 0..63 : A row within tile
    const int sk4  = tid & 3;      // 0..3  : which float4 of the 16 k's
    const int wk   = tid >> 4;     // 0..15 : B k within chunk
    const int wj4  = tid & 15;     // 0..15 : which float4 of 64 j's

    const float rs = 1.0f / fmaxf(cnt[i0 + srow], 1.0f);

    float acc[4][4] = {};

    for (int kk = 0; kk < 32; ++kk) {
        const int kbase = kk * 16;
        // ---- stage A (transposed, scaled if in agg half) ----
        const float* aptr;
        float scale;
        if (kbase < DD) {
            aptr = AGG + (size_t)(i0 + srow) * DD + kbase + sk4 * 4;
            scale = rs;
        } else {
            aptr = XT + (size_t)(i0 + srow) * DD + (kbase - DD) + sk4 * 4;
            scale = 1.0f;
        }
        const float4 av = *(const float4*)aptr;
        As[sk4 * 4 + 0][srow] = av.x * scale;
        As[sk4 * 4 + 1][srow] = av.y * scale;
        As[sk4 * 4 + 2][srow] = av.z * scale;
        As[sk4 * 4 + 3][srow] = av.w * scale;
        // ---- stage B ----
        const float4 bv = *(const float4*)(WT + (size_t)(kbase + wk) * DD + j0 + wj4 * 4);
        *(float4*)&Bs[wk][wj4 * 4] = bv;
        __syncthreads();

        // ---- compute ----
#pragma unroll
        for (int k = 0; k < 16; ++k) {
            const float4 a4 = *(const float4*)&As[k][ty * 4];
            const float4 b4 = *(const float4*)&Bs[k][tx * 4];
            const float ar[4] = {a4.x, a4.y, a4.z, a4.w};
            const float br[4] = {b4.x, b4.y, b4.z, b4.w};
#pragma unroll
            for (int r = 0; r < 4; ++r)
#pragma unroll
                for (int c = 0; c < 4; ++c)
                    acc[r][c] += ar[r] * br[c];
        }
        __syncthreads();
    }

    // ---- epilogue: bias (+relu), store ----
    const float4 bb = *(const float4*)&bias[j0 + tx * 4];
    const float bias4[4] = {bb.x, bb.y, bb.z, bb.w};
#pragma unroll
    for (int r = 0; r < 4; ++r) {
        const int i = i0 + ty * 4 + r;
        float o[4];
#pragma unroll
        for (int c = 0; c < 4; ++c) {
            o[c] = acc[r][c] + bias4[c];
            if (do_relu) o[c] = fmaxf(o[c], 0.0f);
        }
        float4 ov = {o[0], o[1], o[2], o[3]};
        *(float4*)&OUT[(size_t)i * DD + j0 + tx * 4] = ov;
    }
}

// ---------------------------------------------------------------------------
extern "C" void kernel_launch(void* const* d_in, const int* in_sizes, int n_in,
                              void* d_out, int out_size, void* d_ws, size_t ws_size,
                              hipStream_t stream) {
    const float* x    = (const float*)d_in[0];
    const int*   src0 = (const int*)d_in[1];
    const int*   dst0 = (const int*)d_in[2];
    const int*   src1 = (const int*)d_in[3];
    const int*   dst1 = (const int*)d_in[4];
    const float* Wl0  = (const float*)d_in[5];
    const float* bl0  = (const float*)d_in[6];
    const float* Wr0  = (const float*)d_in[7];
    const float* Wl1  = (const float*)d_in[8];
    const float* bl1  = (const float*)d_in[9];
    const float* Wr1  = (const float*)d_in[10];

    const int E0 = in_sizes[1];
    const int E1 = in_sizes[3];
    const int N1 = 22528;
    const int N2 = 2048;

    float* ws   = (float*)d_ws;
    float* agg0 = ws;                              // N1*256
    float* agg1 = agg0 + (size_t)N1 * DD;          // N2*256
    float* cnt0 = agg1 + (size_t)N2 * DD;          // N1
    float* cnt1 = cnt0 + N1;                       // N2
    float* h    = cnt1 + N2;                       // N1*256
    float* WT0  = h + (size_t)N1 * DD;             // 512*256
    float* WT1  = WT0 + 512 * DD;                  // 512*256

    // zero accumulators (agg0, agg1, cnt0, cnt1 are contiguous)
    size_t zero_bytes = ((size_t)N1 * DD + (size_t)N2 * DD + N1 + N2) * sizeof(float);
    hipMemsetAsync(agg0, 0, zero_bytes, stream);

    // build concatenated transposed weights
    build_wt_kernel<<<512, 256, 0, stream>>>(Wl0, Wr0, WT0);
    build_wt_kernel<<<512, 256, 0, stream>>>(Wl1, Wr1, WT1);

    // layer 0 aggregate
    scatter_kernel<<<4096, 256, 0, stream>>>(x, src0, dst0, agg0, cnt0, E0);
    // layer 0 gemm (+bias, relu) -> h
    sage_gemm_kernel<<<dim3(N1 / 64, 4), 256, 0, stream>>>(agg0, x, cnt0, WT0, bl0, h, 1);

    // layer 1 aggregate (from h)
    scatter_kernel<<<2048, 256, 0, stream>>>(h, src1, dst1, agg1, cnt1, E1);
    // layer 1 gemm (+bias) -> out
    sage_gemm_kernel<<<dim3(N2 / 64, 4), 256, 0, stream>>>(agg1, h, cnt1, WT1, bl1,
                                                           (float*)d_out, 0);
}

// Round 2
// 288.000 us; speedup vs baseline: 4.7102x; 4.7102x over previous
//
#include <hip/hip_runtime.h>
#include <hip/hip_bf16.h>

#define DD 256

// ---------------------------------------------------------------------------
// Build WT[k][j], k in [0,512): k<256 -> Wl[j][k], k>=256 -> Wr[j][k-256]
// ---------------------------------------------------------------------------
__global__ void build_wt_kernel(const float* __restrict__ Wl,
                                const float* __restrict__ Wr,
                                float* __restrict__ WT) {
    int k = blockIdx.x;       // 0..511
    int j = threadIdx.x;      // 0..255
    float v = (k < DD) ? Wl[j * DD + k] : Wr[j * DD + (k - DD)];
    WT[k * DD + j] = v;
}

// ---------------------------------------------------------------------------
// CSR build: histogram of dst
// ---------------------------------------------------------------------------
__global__ void hist_kernel(const int* __restrict__ dst, int* __restrict__ hist,
                            int E) {
    int stride = gridDim.x * blockDim.x;
    for (int e = blockIdx.x * blockDim.x + threadIdx.x; e < E; e += stride)
        atomicAdd(&hist[dst[e]], 1);
}

// Single-block exclusive scan: rowptr[i] = sum_{k<i} hist[k]; rowptr[N] = E.
// Also initializes cursor[i] = rowptr[i].
__global__ __launch_bounds__(1024)
void scan_kernel(const int* __restrict__ hist, int* __restrict__ rowptr,
                 int* __restrict__ cursor, int N) {
    __shared__ int sums[1024];
    const int tid = threadIdx.x;
    const int per = (N + 1023) >> 10;
    const int start = tid * per;
    const int end = min(start + per, N);
    int s = 0;
    for (int i = start; i < end; ++i) s += hist[i];
    sums[tid] = s;
    __syncthreads();
    // Hillis-Steele inclusive scan
    for (int d = 1; d < 1024; d <<= 1) {
        int t = (tid >= d) ? sums[tid - d] : 0;
        __syncthreads();
        sums[tid] += t;
        __syncthreads();
    }
    int off = sums[tid] - s;   // exclusive prefix
    for (int i = start; i < end; ++i) {
        rowptr[i] = off;
        cursor[i] = off;
        off += hist[i];
    }
    if (tid == 1023) rowptr[N] = off;
}

// Bucket-fill: eidx[pos] = src[e] grouped by dst.
__global__ void fill_kernel(const int* __restrict__ src, const int* __restrict__ dst,
                            int* __restrict__ cursor, int* __restrict__ eidx, int E) {
    int stride = gridDim.x * blockDim.x;
    for (int e = blockIdx.x * blockDim.x + threadIdx.x; e < E; e += stride) {
        int p = atomicAdd(&cursor[dst[e]], 1);
        eidx[p] = src[e];
    }
}

// ---------------------------------------------------------------------------
// Gather-mean: one wave per target node. Lane l accumulates float4 at col 4l.
// AGG[n] = mean of X[eidx[rowptr[n]..rowptr[n+1])].
// ---------------------------------------------------------------------------
__global__ __launch_bounds__(256)
void gather_mean_kernel(const float* __restrict__ X, const int* __restrict__ rowptr,
                        const int* __restrict__ eidx, float* __restrict__ AGG, int N) {
    const int wave = (blockIdx.x * blockDim.x + threadIdx.x) >> 6;
    const int lane = threadIdx.x & 63;
    if (wave >= N) return;
    const int beg = rowptr[wave];
    const int end = rowptr[wave + 1];
    float4 acc = {0.f, 0.f, 0.f, 0.f};
    int j = beg;
    for (; j + 1 < end; j += 2) {
        int s0 = eidx[j];
        int s1 = eidx[j + 1];
        float4 v0 = *(const float4*)(X + (size_t)s0 * DD + lane * 4);
        float4 v1 = *(const float4*)(X + (size_t)s1 * DD + lane * 4);
        acc.x += v0.x + v1.x;
        acc.y += v0.y + v1.y;
        acc.z += v0.z + v1.z;
        acc.w += v0.w + v1.w;
    }
    if (j < end) {
        int s0 = eidx[j];
        float4 v0 = *(const float4*)(X + (size_t)s0 * DD + lane * 4);
        acc.x += v0.x; acc.y += v0.y; acc.z += v0.z; acc.w += v0.w;
    }
    const float sc = 1.0f / fmaxf((float)(end - beg), 1.0f);
    float4 o = {acc.x * sc, acc.y * sc, acc.z * sc, acc.w * sc};
    *(float4*)(AGG + (size_t)wave * DD + lane * 4) = o;
}

// ---------------------------------------------------------------------------
// Fused SAGE GEMM: OUT[i][j] = act( AGG[i] . Wl[j,:] + X[i] . Wr[j,:] + b[j] )
// C = Acat @ WT + bias, Acat = [AGG | X] (K=512). AGG already mean-scaled.
// 64x64 tile, 256 threads, 4x4 micro-tile, BK=16.
// ---------------------------------------------------------------------------
__global__ __launch_bounds__(256)
void sage_gemm_kernel(const float* __restrict__ AGG,
                      const float* __restrict__ XT,
                      const float* __restrict__ WT,   // [512][256]
                      const float* __restrict__ bias, // [256]
                      float* __restrict__ OUT,
                      int do_relu) {
    __shared__ float As[16][68];
    __shared__ float Bs[16][68];

    const int tid = threadIdx.x;
    const int tx = tid & 15;
    const int ty = tid >> 4;
    const int i0 = blockIdx.x * 64;
    const int j0 = blockIdx.y * 64;

    const int srow = tid >> 2;
    const int sk4  = tid & 3;
    const int wk   = tid >> 4;
    const int wj4  = tid & 15;

    float acc[4][4] = {};

    for (int kk = 0; kk < 32; ++kk) {
        const int kbase = kk * 16;
        const float* aptr = (kbase < DD)
            ? AGG + (size_t)(i0 + srow) * DD + kbase + sk4 * 4
            : XT + (size_t)(i0 + srow) * DD + (kbase - DD) + sk4 * 4;
        const float4 av = *(const float4*)aptr;
        As[sk4 * 4 + 0][srow] = av.x;
        As[sk4 * 4 + 1][srow] = av.y;
        As[sk4 * 4 + 2][srow] = av.z;
        As[sk4 * 4 + 3][srow] = av.w;
        const float4 bv = *(const float4*)(WT + (size_t)(kbase + wk) * DD + j0 + wj4 * 4);
        *(float4*)&Bs[wk][wj4 * 4] = bv;
        __syncthreads();

#pragma unroll
        for (int k = 0; k < 16; ++k) {
            const float4 a4 = *(const float4*)&As[k][ty * 4];
            const float4 b4 = *(const float4*)&Bs[k][tx * 4];
            const float ar[4] = {a4.x, a4.y, a4.z, a4.w};
            const float br[4] = {b4.x, b4.y, b4.z, b4.w};
#pragma unroll
            for (int r = 0; r < 4; ++r)
#pragma unroll
                for (int c = 0; c < 4; ++c)
                    acc[r][c] += ar[r] * br[c];
        }
        __syncthreads();
    }

    const float4 bb = *(const float4*)&bias[j0 + tx * 4];
    const float bias4[4] = {bb.x, bb.y, bb.z, bb.w};
#pragma unroll
    for (int r = 0; r < 4; ++r) {
        const int i = i0 + ty * 4 + r;
        float o[4];
#pragma unroll
        for (int c = 0; c < 4; ++c) {
            o[c] = acc[r][c] + bias4[c];
            if (do_relu) o[c] = fmaxf(o[c], 0.0f);
        }
        float4 ov = {o[0], o[1], o[2], o[3]};
        *(float4*)&OUT[(size_t)i * DD + j0 + tx * 4] = ov;
    }
}

// ---------------------------------------------------------------------------
extern "C" void kernel_launch(void* const* d_in, const int* in_sizes, int n_in,
                              void* d_out, int out_size, void* d_ws, size_t ws_size,
                              hipStream_t stream) {
    const float* x    = (const float*)d_in[0];
    const int*   src0 = (const int*)d_in[1];
    const int*   dst0 = (const int*)d_in[2];
    const int*   src1 = (const int*)d_in[3];
    const int*   dst1 = (const int*)d_in[4];
    const float* Wl0  = (const float*)d_in[5];
    const float* bl0  = (const float*)d_in[6];
    const float* Wr0  = (const float*)d_in[7];
    const float* Wl1  = (const float*)d_in[8];
    const float* bl1  = (const float*)d_in[9];
    const float* Wr1  = (const float*)d_in[10];

    const int E0 = in_sizes[1];
    const int E1 = in_sizes[3];
    const int N1 = 22528;
    const int N2 = 2048;

    float* ws   = (float*)d_ws;
    float* agg0 = ws;                               // N1*256 (reused as agg1)
    float* h    = agg0 + (size_t)N1 * DD;           // N1*256
    float* WT0  = h + (size_t)N1 * DD;              // 512*256
    float* WT1  = WT0 + 512 * DD;                   // 512*256

    int* hist0   = (int*)(WT1 + 512 * DD);          // N1
    int* rowptr0 = hist0 + N1;                      // N1+1
    int* cursor0 = rowptr0 + N1 + 1;                // N1
    int* eidx0   = cursor0 + N1;                    // E0
    int* hist1   = eidx0 + E0;                      // N2
    int* rowptr1 = hist1 + N2;                      // N2+1
    int* cursor1 = rowptr1 + N2 + 1;                // N2
    int* eidx1   = cursor1 + N2;                    // E1
    float* agg1  = agg0;                            // reuse (N2*256)

    // zero histograms
    hipMemsetAsync(hist0, 0, (size_t)N1 * sizeof(int), stream);
    hipMemsetAsync(hist1, 0, (size_t)N2 * sizeof(int), stream);

    // weights concat-transpose
    build_wt_kernel<<<512, 256, 0, stream>>>(Wl0, Wr0, WT0);
    build_wt_kernel<<<512, 256, 0, stream>>>(Wl1, Wr1, WT1);

    // ---- layer 0 CSR + gather + gemm ----
    hist_kernel<<<512, 256, 0, stream>>>(dst0, hist0, E0);
    scan_kernel<<<1, 1024, 0, stream>>>(hist0, rowptr0, cursor0, N1);
    fill_kernel<<<512, 256, 0, stream>>>(src0, dst0, cursor0, eidx0, E0);
    gather_mean_kernel<<<(N1 * 64 + 255) / 256, 256, 0, stream>>>(x, rowptr0, eidx0,
                                                                  agg0, N1);
    sage_gemm_kernel<<<dim3(N1 / 64, 4), 256, 0, stream>>>(agg0, x, WT0, bl0, h, 1);

    // ---- layer 1 CSR + gather + gemm ----
    hist_kernel<<<256, 256, 0, stream>>>(dst1, hist1, E1);
    scan_kernel<<<1, 1024, 0, stream>>>(hist1, rowptr1, cursor1, N2);
    fill_kernel<<<256, 256, 0, stream>>>(src1, dst1, cursor1, eidx1, E1);
    gather_mean_kernel<<<(N2 * 64 + 255) / 256, 256, 0, stream>>>(h, rowptr1, eidx1,
                                                                  agg1, N2);
    sage_gemm_kernel<<<dim3(N2 / 64, 4), 256, 0, stream>>>(agg1, h, WT1, bl1,
                                                           (float*)d_out, 0);
}

// Round 3
// 224.239 us; speedup vs baseline: 6.0495x; 1.2843x over previous
//
#include <hip/hip_runtime.h>
#include <hip/hip_bf16.h>

#define N1C 22528
#define N2C 2048

typedef __attribute__((ext_vector_type(8))) short bf16x8;
typedef __attribute__((ext_vector_type(4))) float f32x4;

__device__ __forceinline__ short f2bf(float f) {
    union { float f; unsigned u; } x; x.f = f;
    unsigned r = x.u + 0x7fff + ((x.u >> 16) & 1);   // RNE
    return (short)(r >> 16);
}
__device__ __forceinline__ float bf2f(unsigned short u) {
    union { unsigned u; float f; } x; x.u = ((unsigned)u) << 16;
    return x.f;
}

// ---------------------------------------------------------------------------
// Prep: zero histograms + build Wcat{0,1} bf16 [256][512] = [Wl | Wr] rows.
// ---------------------------------------------------------------------------
__global__ void prep_kernel(const float* __restrict__ Wl0, const float* __restrict__ Wr0,
                            const float* __restrict__ Wl1, const float* __restrict__ Wr1,
                            short* __restrict__ Wcat0, short* __restrict__ Wcat1,
                            int* __restrict__ hist0, int* __restrict__ hist1) {
    const int stride = gridDim.x * blockDim.x;
    const int tid0 = blockIdx.x * blockDim.x + threadIdx.x;
    for (int i = tid0; i < 2 * 256 * 512; i += stride) {
        int layer = i >> 17;
        int r = i & ((1 << 17) - 1);
        int j = r >> 9, k = r & 511;
        const float* Wl = layer ? Wl1 : Wl0;
        const float* Wr = layer ? Wr1 : Wr0;
        float v = (k < 256) ? Wl[j * 256 + k] : Wr[j * 256 + (k - 256)];
        (layer ? Wcat1 : Wcat0)[r] = f2bf(v);
    }
    for (int i = tid0; i < N1C + N2C; i += stride) {
        if (i < N1C) hist0[i] = 0; else hist1[i - N1C] = 0;
    }
}

// ---------------------------------------------------------------------------
// CSR build (both layers in one launch)
// ---------------------------------------------------------------------------
__global__ void hist_both_kernel(const int* __restrict__ dst0, int E0,
                                 const int* __restrict__ dst1, int E1,
                                 int* __restrict__ hist0, int* __restrict__ hist1) {
    const int stride = gridDim.x * blockDim.x;
    for (int i = blockIdx.x * blockDim.x + threadIdx.x; i < E0 + E1; i += stride) {
        if (i < E0) atomicAdd(&hist0[dst0[i]], 1);
        else        atomicAdd(&hist1[dst1[i - E0]], 1);
    }
}

__global__ __launch_bounds__(1024)
void scan_both_kernel(const int* __restrict__ hist0, int* __restrict__ rowptr0,
                      int* __restrict__ cursor0,
                      const int* __restrict__ hist1, int* __restrict__ rowptr1,
                      int* __restrict__ cursor1) {
    __shared__ int sums[1024];
    const int N = (blockIdx.x == 0) ? N1C : N2C;
    const int* hist   = (blockIdx.x == 0) ? hist0 : hist1;
    int* rowptr       = (blockIdx.x == 0) ? rowptr0 : rowptr1;
    int* cursor       = (blockIdx.x == 0) ? cursor0 : cursor1;
    const int tid = threadIdx.x;
    const int per = (N + 1023) >> 10;
    const int start = tid * per;
    const int end = min(start + per, N);
    int s = 0;
    for (int i = start; i < end; ++i) s += hist[i];
    sums[tid] = s;
    __syncthreads();
    for (int d = 1; d < 1024; d <<= 1) {
        int t = (tid >= d) ? sums[tid - d] : 0;
        __syncthreads();
        sums[tid] += t;
        __syncthreads();
    }
    int off = sums[tid] - s;
    for (int i = start; i < end; ++i) {
        rowptr[i] = off;
        cursor[i] = off;
        off += hist[i];
    }
    if (tid == 1023) rowptr[N] = off;
}

__global__ void fill_both_kernel(const int* __restrict__ src0, const int* __restrict__ dst0, int E0,
                                 const int* __restrict__ src1, const int* __restrict__ dst1, int E1,
                                 int* __restrict__ cursor0, int* __restrict__ eidx0,
                                 int* __restrict__ cursor1, int* __restrict__ eidx1) {
    const int stride = gridDim.x * blockDim.x;
    for (int i = blockIdx.x * blockDim.x + threadIdx.x; i < E0 + E1; i += stride) {
        if (i < E0) {
            int p = atomicAdd(&cursor0[dst0[i]], 1);
            eidx0[p] = src0[i];
        } else {
            int p = atomicAdd(&cursor1[dst1[i - E0]], 1);
            eidx1[p] = src1[i - E0];
        }
    }
}

// ---------------------------------------------------------------------------
// Gather-mean: one wave per target node; lane covers cols [4l,4l+4).
// Writes bf16 into the LEFT half of Acat [N][512].
// ---------------------------------------------------------------------------
template <bool SRC_F32>
__global__ __launch_bounds__(256)
void gather_mean_kernel(const void* __restrict__ Xv, const int* __restrict__ rowptr,
                        const int* __restrict__ eidx, short* __restrict__ Acat, int N) {
    const int wv = (blockIdx.x * 256 + threadIdx.x) >> 6;
    const int lane = threadIdx.x & 63;
    if (wv >= N) return;
    const int beg = rowptr[wv];
    const int end = rowptr[wv + 1];
    float a0 = 0.f, a1 = 0.f, a2 = 0.f, a3 = 0.f;
    int j = beg;
    if (SRC_F32) {
        const float* X = (const float*)Xv;
        for (; j + 1 < end; j += 2) {
            int s0 = eidx[j], s1 = eidx[j + 1];
            float4 v0 = *(const float4*)(X + (size_t)s0 * 256 + lane * 4);
            float4 v1 = *(const float4*)(X + (size_t)s1 * 256 + lane * 4);
            a0 += v0.x + v1.x; a1 += v0.y + v1.y;
            a2 += v0.z + v1.z; a3 += v0.w + v1.w;
        }
        if (j < end) {
            float4 v0 = *(const float4*)(X + (size_t)eidx[j] * 256 + lane * 4);
            a0 += v0.x; a1 += v0.y; a2 += v0.z; a3 += v0.w;
        }
    } else {
        const ushort* X = (const ushort*)Xv;
        for (; j + 1 < end; j += 2) {
            int s0 = eidx[j], s1 = eidx[j + 1];
            ushort4 v0 = *(const ushort4*)(X + (size_t)s0 * 256 + lane * 4);
            ushort4 v1 = *(const ushort4*)(X + (size_t)s1 * 256 + lane * 4);
            a0 += bf2f(v0.x) + bf2f(v1.x); a1 += bf2f(v0.y) + bf2f(v1.y);
            a2 += bf2f(v0.z) + bf2f(v1.z); a3 += bf2f(v0.w) + bf2f(v1.w);
        }
        if (j < end) {
            ushort4 v0 = *(const ushort4*)(X + (size_t)eidx[j] * 256 + lane * 4);
            a0 += bf2f(v0.x); a1 += bf2f(v0.y); a2 += bf2f(v0.z); a3 += bf2f(v0.w);
        }
    }
    const float sc = 1.0f / fmaxf((float)(end - beg), 1.0f);
    short4 o;
    o.x = f2bf(a0 * sc); o.y = f2bf(a1 * sc);
    o.z = f2bf(a2 * sc); o.w = f2bf(a3 * sc);
    *(short4*)(Acat + (size_t)wv * 512 + lane * 4) = o;
}

// ---------------------------------------------------------------------------
// Cast x[:N1] fp32 -> RIGHT half of Acat0 (bf16)
// ---------------------------------------------------------------------------
__global__ void xcast_kernel(const float* __restrict__ x, short* __restrict__ Acat0) {
    const int stride = gridDim.x * blockDim.x;
    const int total = N1C * 64;
    for (int u = blockIdx.x * blockDim.x + threadIdx.x; u < total; u += stride) {
        int row = u >> 6;
        int c = (u & 63) * 4;
        float4 v = *(const float4*)(x + (size_t)row * 256 + c);
        short4 o;
        o.x = f2bf(v.x); o.y = f2bf(v.y); o.z = f2bf(v.z); o.w = f2bf(v.w);
        *(short4*)(Acat0 + (size_t)row * 512 + 256 + c) = o;
    }
}

// ---------------------------------------------------------------------------
// MFMA GEMM: C[M][256] = Acat[M][512] @ Wcat[256][512]^T + bias, opt. ReLU.
// Block = 256 thr = 4 waves; block tile 64 rows x 64 cols; wave = 16 rows.
// Per wave: 4 col-tiles of 16, K=512 in 16 steps of 32. No LDS.
// OUT_BF16: store bf16 [M][256] (+ first 2048 rows into out2 right half).
// ---------------------------------------------------------------------------
template <bool RELU, bool OUT_BF16>
__global__ __launch_bounds__(256)
void mfma_gemm_kernel(const short* __restrict__ A, const short* __restrict__ W,
                      const float* __restrict__ bias, void* __restrict__ out,
                      short* __restrict__ out2, int M) {
    const int tid = threadIdx.x;
    const int wave = tid >> 6;
    const int lane = tid & 63;
    const int r0 = blockIdx.x * 64 + wave * 16;
    const int j0 = blockIdx.y * 64;
    const int lrow = lane & 15;
    const int lk = (lane >> 4) * 8;

    const short* arow = A + (size_t)(r0 + lrow) * 512 + lk;
    const short* wbase = W + (size_t)(j0 + lrow) * 512 + lk;

    f32x4 acc[4] = {f32x4{0,0,0,0}, f32x4{0,0,0,0}, f32x4{0,0,0,0}, f32x4{0,0,0,0}};
#pragma unroll
    for (int ks = 0; ks < 16; ++ks) {
        bf16x8 a = *(const bf16x8*)(arow + ks * 32);
#pragma unroll
        for (int c = 0; c < 4; ++c) {
            bf16x8 b = *(const bf16x8*)(wbase + (size_t)c * 16 * 512 + ks * 32);
            acc[c] = __builtin_amdgcn_mfma_f32_16x16x32_bf16(a, b, acc[c], 0, 0, 0);
        }
    }

    const int orow = (lane >> 4) * 4;
#pragma unroll
    for (int c = 0; c < 4; ++c) {
        const int col = j0 + c * 16 + lrow;
        const float bv = bias[col];
#pragma unroll
        for (int i = 0; i < 4; ++i) {
            const int row = r0 + orow + i;
            float v = acc[c][i] + bv;
            if (RELU) v = fmaxf(v, 0.0f);
            if (OUT_BF16) {
                short hv = f2bf(v);
                ((short*)out)[(size_t)row * 256 + col] = hv;
                if (out2 != nullptr && row < N2C)
                    out2[(size_t)row * 512 + 256 + col] = hv;
            } else {
                ((float*)out)[(size_t)row * 256 + col] = v;
            }
        }
    }
}

// ---------------------------------------------------------------------------
extern "C" void kernel_launch(void* const* d_in, const int* in_sizes, int n_in,
                              void* d_out, int out_size, void* d_ws, size_t ws_size,
                              hipStream_t stream) {
    const float* x    = (const float*)d_in[0];
    const int*   src0 = (const int*)d_in[1];
    const int*   dst0 = (const int*)d_in[2];
    const int*   src1 = (const int*)d_in[3];
    const int*   dst1 = (const int*)d_in[4];
    const float* Wl0  = (const float*)d_in[5];
    const float* bl0  = (const float*)d_in[6];
    const float* Wr0  = (const float*)d_in[7];
    const float* Wl1  = (const float*)d_in[8];
    const float* bl1  = (const float*)d_in[9];
    const float* Wr1  = (const float*)d_in[10];

    const int E0 = in_sizes[1];
    const int E1 = in_sizes[3];

    // workspace layout (16B-aligned chunks)
    char* p = (char*)d_ws;
    short* Acat0 = (short*)p;            p += (size_t)N1C * 512 * 2;   // 23.1 MB
    short* h     = (short*)p;            p += (size_t)N1C * 256 * 2;   // 11.5 MB
    short* Acat1 = (short*)p;            p += (size_t)N2C * 512 * 2;   // 2.1 MB
    short* Wcat0 = (short*)p;            p += 256 * 512 * 2;
    short* Wcat1 = (short*)p;            p += 256 * 512 * 2;
    int* hist0   = (int*)p;              p += (size_t)N1C * 4;
    int* cursor0 = (int*)p;              p += (size_t)N1C * 4;
    int* rowptr0 = (int*)p;              p += (size_t)(N1C + 4) * 4;
    int* hist1   = (int*)p;              p += (size_t)N2C * 4;
    int* cursor1 = (int*)p;              p += (size_t)N2C * 4;
    int* rowptr1 = (int*)p;              p += (size_t)(N2C + 4) * 4;
    int* eidx0   = (int*)p;              p += (size_t)E0 * 4;
    int* eidx1   = (int*)p;              p += (size_t)E1 * 4;

    // 1. prep: Wcat bf16 + zero hists
    prep_kernel<<<512, 256, 0, stream>>>(Wl0, Wr0, Wl1, Wr1, Wcat0, Wcat1, hist0, hist1);
    // 2-4. CSR build for both layers
    hist_both_kernel<<<512, 256, 0, stream>>>(dst0, E0, dst1, E1, hist0, hist1);
    scan_both_kernel<<<2, 1024, 0, stream>>>(hist0, rowptr0, cursor0, hist1, rowptr1, cursor1);
    fill_both_kernel<<<512, 256, 0, stream>>>(src0, dst0, E0, src1, dst1, E1,
                                              cursor0, eidx0, cursor1, eidx1);
    // 5. x[:N1] -> Acat0 right half
    xcast_kernel<<<1024, 256, 0, stream>>>(x, Acat0);
    // 6. layer-0 gather-mean -> Acat0 left half
    gather_mean_kernel<true><<<(N1C * 64 + 255) / 256, 256, 0, stream>>>(
        x, rowptr0, eidx0, Acat0, N1C);
    // 7. layer-0 GEMM -> h (bf16) + Acat1 right half
    mfma_gemm_kernel<true, true><<<dim3(N1C / 64, 4), 256, 0, stream>>>(
        Acat0, Wcat0, bl0, h, Acat1, N1C);
    // 8. layer-1 gather-mean (from h) -> Acat1 left half
    gather_mean_kernel<false><<<(N2C * 64 + 255) / 256, 256, 0, stream>>>(
        h, rowptr1, eidx1, Acat1, N2C);
    // 9. layer-1 GEMM -> d_out (fp32)
    mfma_gemm_kernel<false, false><<<dim3(N2C / 64, 4), 256, 0, stream>>>(
        Acat1, Wcat1, bl1, (float*)d_out, nullptr, N2C);
}